// Round 3
// baseline (33.346 us; speedup 1.0000x reference)
//
#include <hip/hip_runtime.h>

#define B_   4
#define K_   8
#define N_   4096       // H*W
#define DV_  32
#define NC_  256        // 2^K_

__device__ __forceinline__ int read_mask(const void* m, int layout, int idx) {
    if (layout == 0) return ((const int*)m)[idx] != 0;
    if (layout == 1) return ((const float*)m)[idx] != 0.0f;
    if (layout == 3) return ((const int*)m)[2 * idx] != 0;  // int64 LE low word
    return ((const unsigned char*)m)[idx] != 0;
}

// Every block scans the same leading 16 KB of the mask buffer (safe under all
// candidate layouts; the u8 buffer is exactly 16 KB) -> identical verdict in
// every block, deterministic.
__device__ __forceinline__ int detect_layout(const void* mask, int tid) {
    __shared__ int ok[3];  // 0:i32, 1:f32, 2:i64
    if (tid < 3) ok[tid] = 1;
    __syncthreads();
    const unsigned int* mi = (const unsigned int*)mask;
    int li32 = 1, lf32 = 1, li64 = 1;
    for (int i = tid; i < 4096; i += 256) {
        unsigned int v = mi[i];
        li32 &= (v <= 1u);
        lf32 &= (v == 0u || v == 0x3F800000u);
        li64 &= ((i & 1) ? (v == 0u) : (v <= 1u));
    }
    if (!li32) atomicAnd(&ok[0], 0);
    if (!lf32) atomicAnd(&ok[1], 0);
    if (!li64) atomicAnd(&ok[2], 0);
    __syncthreads();
    return ok[2] ? 3 : (ok[0] ? 0 : (ok[1] ? 1 : 2));
}

// ONE kernel, grid = B_*16 blocks x 256 threads. Each block:
//   1. redundantly scans its whole batch (z: 128 KB, L2-hot across the 16
//      sibling blocks) -> codes + private evidence histogram in LDS
//   2. 8-stage Kronecker butterfly: W = [[1,t],[t,1]]^{(x)8} applied to
//      [cnt*V | cnt] (256 x 33 tile) gives numerator and denominator
//   3. writes its own 256-query output slice, transposed.
// No workspace, no global atomics, no cross-block dependency.
__global__ void __launch_bounds__(256)
fused_one(const float* __restrict__ z, const void* mask, const float* __restrict__ V,
          const float* __restrict__ mv, const float* __restrict__ temperature,
          float* __restrict__ out) {
    __shared__ float X[NC_ * 33];   // ~33 KB, odd row stride
    __shared__ int hist[NC_];
    __shared__ int red[4];
    int tid = threadIdx.x;
    int b = blockIdx.x >> 4;
    int slice = blockIdx.x & 15;

    int layout = detect_layout(mask, tid);   // contains syncthreads
    hist[tid] = 0;
    __syncthreads();

    // full-batch scan: 16 chunks of 256 n
    const float* zb = z + (size_t)b * K_ * N_;
    int mycode = 0;
    for (int ci = 0; ci < 16; ++ci) {
        int n = (ci << 8) + tid;
        int code = 0;
#pragma unroll
        for (int j = 0; j < K_; ++j) code |= (zb[j * N_ + n] > 0.5f ? 1 : 0) << j;
        if (ci == slice) mycode = code;
        if (read_mask(mask, layout, b * N_ + n)) atomicAdd(&hist[code], 1);
    }
    __syncthreads();

    int c = hist[tid];
    // evidence count = sum of histogram (wave shuffle + LDS across 4 waves)
    int s = c;
#pragma unroll
    for (int off = 32; off; off >>= 1) s += __shfl_down(s, off);
    if ((tid & 63) == 0) red[tid >> 6] = s;
    __syncthreads();
    int evid = red[0] + red[1] + red[2] + red[3];

    float temp = fmaxf(temperature[0], 0.1f);
    float t = __expf(-1.0f / temp);

    // init: X[c][0..31] = cnt[c]*V[c][d], X[c][32] = cnt[c]
    for (int i = tid; i < NC_ * 33; i += 256) {
        int cc = i / 33, col = i - cc * 33;
        float cf = (float)hist[cc];
        X[i] = (col < DV_) ? cf * V[cc * DV_ + col] : cf;
    }
    __syncthreads();

    // 8 butterfly stages: x0' = x0 + t*x1 ; x1' = t*x0 + x1
#pragma unroll
    for (int stg = 0; stg < 8; ++stg) {
        int bit = 1 << stg;
        for (int p = tid; p < 128 * 33; p += 256) {
            int pi = p / 33, col = p - pi * 33;
            int c0 = ((pi >> stg) << (stg + 1)) | (pi & (bit - 1));
            int i0 = c0 * 33 + col, i1 = i0 + bit * 33;
            float x0 = X[i0], x1 = X[i1];
            X[i0] = fmaf(t, x1, x0);
            X[i1] = fmaf(t, x0, x1);
        }
        __syncthreads();
    }

    // own-slice gather + transposed write: out[b][d][slice*256 + tid]
    float* ob = out + (size_t)b * DV_ * N_ + (slice << 8) + tid;
    if (evid == 0) {
#pragma unroll
        for (int d = 0; d < DV_; ++d) ob[d * N_] = mv[d];
    } else {
        float rden = 1.0f / X[mycode * 33 + DV_];
#pragma unroll
        for (int d = 0; d < DV_; ++d) ob[d * N_] = X[mycode * 33 + d] * rden;
    }
}

extern "C" void kernel_launch(void* const* d_in, const int* in_sizes, int n_in,
                              void* d_out, int out_size, void* d_ws, size_t ws_size,
                              hipStream_t stream) {
    const float* z    = (const float*)d_in[0];
    const void*  mask = d_in[1];
    const float* V    = (const float*)d_in[2];
    const float* mv   = (const float*)d_in[3];
    const float* temp = (const float*)d_in[4];
    float* out = (float*)d_out;
    fused_one<<<B_ * 16, 256, 0, stream>>>(z, mask, V, mv, temp, out);
}